// Round 2
// baseline (90.842 us; speedup 1.0000x reference)
//
#include <hip/hip_runtime.h>
#include <math.h>

// DiffRenderer: BS=4, IMG=64, D_STEPS=64, D_SH=61, H1=128
// Inputs: z_shape(4,61), z_extr(4,5), W1(64,128), b1(128), W2(128,1), b2(1)
// Output: depth_pred (4*64*64) ++ occ (4*64*64), fp32
//
// Mapping: one wave per ray (64 lanes = 64 depth steps). 4 waves/block.
// All weights staged in LDS; cvec (= b1 + z_shape @ W1[3:]) computed in the
// staging phase by waves 2-3 with the exact fmaf chain of the old kernel 1
// (bit-exactness preserves sign(sdf) -> occ).

#define N_RAYS (4 * 64 * 64)

typedef float v2f __attribute__((ext_vector_type(2)));

static __device__ __forceinline__ v2f mk2(float a, float b) {
    v2f r; r.x = a; r.y = b; return r;
}

__global__ __launch_bounds__(256, 4) void render_kernel(
    const float* __restrict__ z_shape,   // (4,61)
    const float* __restrict__ z_extr,    // (4,5): scale, tx, ty, tz, alpha
    const float* __restrict__ W1,        // (64,128) row-major
    const float* __restrict__ b1,        // (128)
    const float* __restrict__ W2,        // (128,1)
    const float* __restrict__ b2,        // (1)
    float* __restrict__ out)             // depth[16384] then occ[16384]
{
    // LDS layout: [0:384) W1 rows 0-2, [384:512) cvec for this block's batch,
    // [512:640) W2.
    __shared__ float sW[640];
    const int tid = threadIdx.x;
    const int bb  = blockIdx.x >> 10;    // 1024 blocks per batch -> block-uniform

    sW[tid] = W1[tid];                   // W1 rows 0,1
    if (tid < 128) {
        sW[256 + tid] = W1[256 + tid];   // W1 row 2
    } else {
        const int h = tid - 128;         // 0..127
        sW[512 + h] = W2[h];
        float a = b1[h];
        #pragma unroll 8
        for (int f = 0; f < 61; ++f)
            a = fmaf(z_shape[bb * 61 + f], W1[(3 + f) * 128 + h], a);
        sW[384 + h] = a;                 // cvec[bb][h], identical chain to before
    }
    __syncthreads();

    const int lane = tid & 63;
    // force wave-uniformity so batch-dependent loads become scalar loads
    const int wave = __builtin_amdgcn_readfirstlane(tid >> 6);
    const int ray  = blockIdx.x * 4 + wave;       // 0..16383
    const int b    = ray >> 12;                   // batch
    const int rem  = ray & 4095;
    const int yi   = rem >> 6;                    // pixel row (y)
    const int xj   = rem & 63;                    // pixel col (x)

    // per-batch extrinsics (wave-uniform)
    const float scale = z_extr[b * 5 + 0];
    const float tx    = z_extr[b * 5 + 1];
    const float ty    = z_extr[b * 5 + 2];
    const float tz    = z_extr[b * 5 + 3];
    const float alpha = z_extr[b * 5 + 4];

    const float a  = 3.14159274101257324f * alpha;   // fp32(pi) * alpha
    const float ca = cosf(a);
    const float sa = sinf(a);
    const float s_obj = 1.0f / scale;                // reference: 1/z_extr[:,0]
    const float s_inv = 1.0f / s_obj;                // reference: 1/s_obj
    const float T = tz + 2.5f;                       // bb_depth

    // depth sample for this lane
    const float step = 2.0f / 63.0f;
    const float zk  = -1.0f + (float)lane * step;
    const float Z   = zk * s_inv + T;                // camera-space depth
    const float zk1 = -1.0f + (float)(lane + 1) * step;
    const float Z1  = zk1 * s_inv + T;

    // pixel -> camera ray direction via K_inv: [(x-c)/f, (y-c)/f, 1]
    const float kf  = 1.0f / 70.0f;
    const float kc  = -(31.5f / 70.0f);
    const float u = fmaf((float)xj, kf, kc);
    const float v = fmaf((float)yi, kf, kc);

    // world point = depth * K_inv*p - t  (R_t = I, t = [0,0,2.5])
    // object coords = s_obj * R_obj @ (world - t_obj)
    const float qx = Z * u - tx;
    const float qy = Z * v - ty;
    const float qz = (Z - 2.5f) - tz;
    const float X0 = s_obj * (ca * qx - sa * qy);
    const float X1 = s_obj * (sa * qx + ca * qy);
    const float X2 = s_obj * qz;

    // MLP: acc = b2 + sum_j relu(fma(X0,W0j, fma(X1,W1j, fma(X2,W2j, c_j)))) * W2j
    // Neuron chains are independent -> packed pairwise (v_pk_fma_f32), which is
    // per-component IEEE fma = bit-exact. acc chain stays scalar & in order.
    const float4* __restrict__ w0 = (const float4*)(sW);
    const float4* __restrict__ w1 = (const float4*)(sW + 128);
    const float4* __restrict__ w2 = (const float4*)(sW + 256);
    const float4* __restrict__ wc = (const float4*)(sW + 384);
    const float4* __restrict__ wo = (const float4*)(sW + 512);

    const v2f X0v = mk2(X0, X0);
    const v2f X1v = mk2(X1, X1);
    const v2f X2v = mk2(X2, X2);
    const v2f zero2 = mk2(0.0f, 0.0f);

    float acc = b2[0];
    #pragma unroll 4
    for (int q = 0; q < 32; ++q) {
        const float4 a0 = w0[q];
        const float4 a1 = w1[q];
        const float4 a2 = w2[q];
        const float4 cc = wc[q];
        const float4 ww = wo[q];
        v2f lo = __builtin_elementwise_fma(X2v, mk2(a2.x, a2.y), mk2(cc.x, cc.y));
        lo = __builtin_elementwise_fma(X1v, mk2(a1.x, a1.y), lo);
        lo = __builtin_elementwise_fma(X0v, mk2(a0.x, a0.y), lo);
        lo = __builtin_elementwise_max(lo, zero2);
        v2f hi = __builtin_elementwise_fma(X2v, mk2(a2.z, a2.w), mk2(cc.z, cc.w));
        hi = __builtin_elementwise_fma(X1v, mk2(a1.z, a1.w), hi);
        hi = __builtin_elementwise_fma(X0v, mk2(a0.z, a0.w), hi);
        hi = __builtin_elementwise_max(hi, zero2);
        acc = fmaf(lo.x, ww.x, acc);
        acc = fmaf(lo.y, ww.y, acc);
        acc = fmaf(hi.x, ww.z, acc);
        acc = fmaf(hi.y, ww.w, acc);
    }
    const float sdf = tanhf(acc);

    // zero-crossing detection along depth (lane axis)
    const unsigned long long mask  = __ballot(sdf > 0.0f);
    const unsigned long long cross = mask & ~(mask >> 1) & 0x7fffffffffffffffULL;

    const bool isC = (cross >> lane) & 1ULL;
    const float sdf_next = __shfl_down(sdf, 1, 64);

    float d1 = isC ? Z        : 100.0f;
    float d2 = isC ? Z1       : 100.0f;
    float s1 = isC ? sdf      : 0.0f;
    float s2 = isC ? sdf_next : 0.0f;

    #pragma unroll
    for (int m = 1; m < 64; m <<= 1) {
        d1 = fminf(d1, __shfl_xor(d1, m, 64));
        d2 = fminf(d2, __shfl_xor(d2, m, 64));
        s1 += __shfl_xor(s1, m, 64);
        s2 += __shfl_xor(s2, m, 64);
    }

    if (lane == 0) {
        float occ = (cross != 0ULL) ? 1.0f : 0.0f;
        float depth = 0.0f;
        if (cross != 0ULL)
            depth = d1 - s1 / (s2 - s1 - 1e-6f) * (d2 - d1);
        out[ray]          = depth;   // depth_pred, (b, yi, xj) == ray
        out[N_RAYS + ray] = occ;     // occ
    }
}

extern "C" void kernel_launch(void* const* d_in, const int* in_sizes, int n_in,
                              void* d_out, int out_size, void* d_ws, size_t ws_size,
                              hipStream_t stream) {
    const float* z_shape = (const float*)d_in[0];   // (4,61)
    const float* z_extr  = (const float*)d_in[1];   // (4,5)
    const float* W1      = (const float*)d_in[2];   // (64,128)
    const float* b1      = (const float*)d_in[3];   // (128)
    const float* W2      = (const float*)d_in[4];   // (128,1)
    const float* b2      = (const float*)d_in[5];   // (1)
    float* out = (float*)d_out;

    render_kernel<<<N_RAYS / 4, 256, 0, stream>>>(
        z_shape, z_extr, W1, b1, W2, b2, out);
}

// Round 3
// 88.830 us; speedup vs baseline: 1.0227x; 1.0227x over previous
//
#include <hip/hip_runtime.h>
#include <math.h>

// DiffRenderer: BS=4, IMG=64, D_STEPS=64, D_SH=61, H1=128
// Inputs: z_shape(4,61), z_extr(4,5), W1(64,128), b1(128), W2(128,1), b2(1)
// Output: depth_pred (4*64*64) ++ occ (4*64*64), fp32
//
// Mapping: one wave per ray (64 lanes = 64 depth steps), 4 waves/block.
// Weights are WAVE-UNIFORM -> forced onto the scalar pipe (s_load_dwordx4
// into SGPRs via inline asm) instead of LDS/VMEM, which serialized on the
// per-lane pipes in rounds 1-2. All fp math chains are bit-identical to the
// previously passing kernels (absmax 0.0): sign(sdf) drives occ, so no
// reassociation anywhere.

#define N_RAYS (4 * 64 * 64)

typedef float v2f __attribute__((ext_vector_type(2)));
typedef float f4v __attribute__((ext_vector_type(4)));

static __device__ __forceinline__ v2f mk2(float a, float b) {
    v2f r; r.x = a; r.y = b; return r;
}

// scalar load of 4 dwords into SGPRs; ptr must be wave-uniform, 16B-aligned
#define SLOAD4(dst, ptr) \
    asm volatile("s_load_dwordx4 %0, %1, 0x0" : "=s"(dst) : "s"(ptr))

// ---------------------------------------------------------------------------
// Kernel 1: cvec[b][h] = b1[h] + sum_f z_shape[b,f] * W1[3+f, h]   (4 x 128)
// ---------------------------------------------------------------------------
__global__ __launch_bounds__(512) void precompute_cvec(
    const float* __restrict__ z_shape,   // (4,61)
    const float* __restrict__ W1,        // (64,128) row-major
    const float* __restrict__ b1,        // (128)
    float* __restrict__ cvec)            // (4,128)
{
    int tid = blockIdx.x * blockDim.x + threadIdx.x;
    if (tid >= 4 * 128) return;
    int b = tid >> 7;
    int h = tid & 127;
    float acc = b1[h];
    #pragma unroll
    for (int f = 0; f < 61; ++f)
        acc = fmaf(z_shape[b * 61 + f], W1[(3 + f) * 128 + h], acc);
    cvec[tid] = acc;
}

// ---------------------------------------------------------------------------
// Kernel 2: one wave per ray; lane = depth step k. Weights via SMEM.
// ---------------------------------------------------------------------------
__global__ __launch_bounds__(256, 8) void render_kernel(
    const float* __restrict__ z_extr,    // (4,5): scale, tx, ty, tz, alpha
    const float* __restrict__ W1,        // (64,128)
    const float* __restrict__ W2,        // (128,1)
    const float* __restrict__ b2,        // (1)
    const float* __restrict__ cvec,      // (4,128) in d_ws
    float* __restrict__ out)             // depth[16384] then occ[16384]
{
    const int tid  = threadIdx.x;
    const int lane = tid & 63;
    const int wave = __builtin_amdgcn_readfirstlane(tid >> 6);
    const int ray  = blockIdx.x * 4 + wave;       // 0..16383
    const int b    = ray >> 12;                   // batch
    const int rem  = ray & 4095;
    const int yi   = rem >> 6;                    // pixel row (y)
    const int xj   = rem & 63;                    // pixel col (x)

    // per-batch extrinsics (wave-uniform)
    const float scale = z_extr[b * 5 + 0];
    const float tx    = z_extr[b * 5 + 1];
    const float ty    = z_extr[b * 5 + 2];
    const float tz    = z_extr[b * 5 + 3];
    const float alpha = z_extr[b * 5 + 4];

    const float a  = 3.14159274101257324f * alpha;   // fp32(pi) * alpha
    const float ca = cosf(a);
    const float sa = sinf(a);
    const float s_obj = 1.0f / scale;                // reference: 1/z_extr[:,0]
    const float s_inv = 1.0f / s_obj;                // reference: 1/s_obj
    const float T = tz + 2.5f;                       // bb_depth

    // depth sample for this lane
    const float step = 2.0f / 63.0f;
    const float zk  = -1.0f + (float)lane * step;
    const float Z   = zk * s_inv + T;                // camera-space depth
    const float zk1 = -1.0f + (float)(lane + 1) * step;
    const float Z1  = zk1 * s_inv + T;

    // pixel -> camera ray direction via K_inv: [(x-c)/f, (y-c)/f, 1]
    const float kf  = 1.0f / 70.0f;
    const float kc  = -(31.5f / 70.0f);
    const float u = fmaf((float)xj, kf, kc);
    const float v = fmaf((float)yi, kf, kc);

    // world point = depth * K_inv*p - t  (R_t = I, t = [0,0,2.5])
    // object coords = s_obj * R_obj @ (world - t_obj)
    const float qx = Z * u - tx;
    const float qy = Z * v - ty;
    const float qz = (Z - 2.5f) - tz;
    const float X0 = s_obj * (ca * qx - sa * qy);
    const float X1 = s_obj * (sa * qx + ca * qy);
    const float X2 = s_obj * qz;

    const v2f X0v = mk2(X0, X0);
    const v2f X1v = mk2(X1, X1);
    const v2f X2v = mk2(X2, X2);
    const v2f zero2 = mk2(0.0f, 0.0f);

    const float* __restrict__ cb = cvec + b * 128;

    // MLP: acc = b2 + sum_j relu(fma(X0,w0j, fma(X1,w1j, fma(X2,w2j, c_j)))) * w2j
    // 16 chunks of 8 neurons; weights land in SGPRs (scalar pipe).
    float acc = b2[0];
    #pragma unroll 4
    for (int q = 0; q < 16; ++q) {
        const int o = q * 8;
        f4v a0l, a0h, a1l, a1h, a2l, a2h, ccl, cch, wol, woh;
        SLOAD4(a0l, W1 + o);            SLOAD4(a0h, W1 + o + 4);
        SLOAD4(a1l, W1 + 128 + o);      SLOAD4(a1h, W1 + 128 + o + 4);
        SLOAD4(a2l, W1 + 256 + o);      SLOAD4(a2h, W1 + 256 + o + 4);
        SLOAD4(ccl, cb + o);            SLOAD4(cch, cb + o + 4);
        SLOAD4(wol, W2 + o);            SLOAD4(woh, W2 + o + 4);
        // SMEM returns out of order -> full drain, tied to all loaded regs so
        // no use can be scheduled before the wait.
        asm volatile("s_waitcnt lgkmcnt(0)"
                     : "+s"(a0l), "+s"(a0h), "+s"(a1l), "+s"(a1h),
                       "+s"(a2l), "+s"(a2h), "+s"(ccl), "+s"(cch),
                       "+s"(wol), "+s"(woh));

        // neurons o+0..o+3
        {
            v2f lo = __builtin_elementwise_fma(X2v, mk2(a2l.x, a2l.y), mk2(ccl.x, ccl.y));
            lo = __builtin_elementwise_fma(X1v, mk2(a1l.x, a1l.y), lo);
            lo = __builtin_elementwise_fma(X0v, mk2(a0l.x, a0l.y), lo);
            lo = __builtin_elementwise_max(lo, zero2);
            v2f hi = __builtin_elementwise_fma(X2v, mk2(a2l.z, a2l.w), mk2(ccl.z, ccl.w));
            hi = __builtin_elementwise_fma(X1v, mk2(a1l.z, a1l.w), hi);
            hi = __builtin_elementwise_fma(X0v, mk2(a0l.z, a0l.w), hi);
            hi = __builtin_elementwise_max(hi, zero2);
            acc = fmaf(lo.x, wol.x, acc);
            acc = fmaf(lo.y, wol.y, acc);
            acc = fmaf(hi.x, wol.z, acc);
            acc = fmaf(hi.y, wol.w, acc);
        }
        // neurons o+4..o+7
        {
            v2f lo = __builtin_elementwise_fma(X2v, mk2(a2h.x, a2h.y), mk2(cch.x, cch.y));
            lo = __builtin_elementwise_fma(X1v, mk2(a1h.x, a1h.y), lo);
            lo = __builtin_elementwise_fma(X0v, mk2(a0h.x, a0h.y), lo);
            lo = __builtin_elementwise_max(lo, zero2);
            v2f hi = __builtin_elementwise_fma(X2v, mk2(a2h.z, a2h.w), mk2(cch.z, cch.w));
            hi = __builtin_elementwise_fma(X1v, mk2(a1h.z, a1h.w), hi);
            hi = __builtin_elementwise_fma(X0v, mk2(a0h.z, a0h.w), hi);
            hi = __builtin_elementwise_max(hi, zero2);
            acc = fmaf(lo.x, woh.x, acc);
            acc = fmaf(lo.y, woh.y, acc);
            acc = fmaf(hi.x, woh.z, acc);
            acc = fmaf(hi.y, woh.w, acc);
        }
    }
    const float sdf = tanhf(acc);

    // zero-crossing detection along depth (lane axis)
    const unsigned long long mask  = __ballot(sdf > 0.0f);
    const unsigned long long cross = mask & ~(mask >> 1) & 0x7fffffffffffffffULL;

    const bool isC = (cross >> lane) & 1ULL;
    const float sdf_next = __shfl_down(sdf, 1, 64);

    float d1 = isC ? Z        : 100.0f;
    float d2 = isC ? Z1       : 100.0f;
    float s1 = isC ? sdf      : 0.0f;
    float s2 = isC ? sdf_next : 0.0f;

    #pragma unroll
    for (int m = 1; m < 64; m <<= 1) {
        d1 = fminf(d1, __shfl_xor(d1, m, 64));
        d2 = fminf(d2, __shfl_xor(d2, m, 64));
        s1 += __shfl_xor(s1, m, 64);
        s2 += __shfl_xor(s2, m, 64);
    }

    if (lane == 0) {
        float occ = (cross != 0ULL) ? 1.0f : 0.0f;
        float depth = 0.0f;
        if (cross != 0ULL)
            depth = d1 - s1 / (s2 - s1 - 1e-6f) * (d2 - d1);
        out[ray]          = depth;   // depth_pred, (b, yi, xj) == ray
        out[N_RAYS + ray] = occ;     // occ
    }
}

extern "C" void kernel_launch(void* const* d_in, const int* in_sizes, int n_in,
                              void* d_out, int out_size, void* d_ws, size_t ws_size,
                              hipStream_t stream) {
    const float* z_shape = (const float*)d_in[0];   // (4,61)
    const float* z_extr  = (const float*)d_in[1];   // (4,5)
    const float* W1      = (const float*)d_in[2];   // (64,128)
    const float* b1      = (const float*)d_in[3];   // (128)
    const float* W2      = (const float*)d_in[4];   // (128,1)
    const float* b2      = (const float*)d_in[5];   // (1)
    float* out  = (float*)d_out;
    float* cvec = (float*)d_ws;                     // 4*128 floats scratch

    precompute_cvec<<<1, 512, 0, stream>>>(z_shape, W1, b1, cvec);
    render_kernel<<<N_RAYS / 4, 256, 0, stream>>>(z_extr, W1, W2, b2, cvec, out);
}